// Round 1
// baseline (540.709 us; speedup 1.0000x reference)
//
#include <hip/hip_runtime.h>

// Problem constants (match reference init_kwargs)
#define DD    64
#define LL    262144
#define GG    8
#define JJ    8
#define FGF   16
#define WW    31
#define PAD1  15          // (W-1)/2
#define TILE  1024        // k positions per block
#define BK    4           // k positions per thread
#define NTHR  256
#define ROWLEN (TILE + 2*PAD1 + 2)   // 1056, multiple of 4 for b128 alignment

// Main kernel: interior grouped correlation.
// y[g,f,k] = sum_j sum_w x[rel[g,j], k-15+w] * p[g,f,j,w]
// Edge k (<15 or >=L-15) produce zero-padded values here; a second kernel
// overwrites them with the reference's truncated-window semantics.
__global__ __launch_bounds__(NTHR, 2)
void conv_main(const float* __restrict__ x, const float* __restrict__ p,
               const int* __restrict__ rel, float* __restrict__ out)
{
    __shared__ float ldsx[JJ][ROWLEN];

    const int t    = threadIdx.x;          // 0..255
    const int g    = blockIdx.y;           // group
    const long base = (long)blockIdx.x * TILE;

    // Stage x[rel[g,j], base-15 .. base+TILE+14] into LDS (zero-filled OOB).
    for (int j = 0; j < JJ; ++j) {
        const int row = rel[g * JJ + j];
        const float* xr = x + (long)row * LL;
        #pragma unroll
        for (int i = t; i < ROWLEN; i += NTHR) {
            long gi = base - PAD1 + i;
            ldsx[j][i] = (gi >= 0 && gi < LL) ? xr[gi] : 0.0f;
        }
    }
    __syncthreads();

    float acc[FGF][BK];
    #pragma unroll
    for (int f = 0; f < FGF; ++f)
        #pragma unroll
        for (int d = 0; d < BK; ++d) acc[f][d] = 0.0f;

    for (int j = 0; j < JJ; ++j) {
        // Thread's x window: xw[i] = x[base + 4t - 15 + i], i in [0,36)
        float xw[36];
        #pragma unroll
        for (int i = 0; i < 9; ++i) {
            float4 v = *(const float4*)&ldsx[j][4 * t + 4 * i];  // 16B aligned
            xw[4*i+0] = v.x; xw[4*i+1] = v.y; xw[4*i+2] = v.z; xw[4*i+3] = v.w;
        }
        #pragma unroll
        for (int f = 0; f < FGF; ++f) {
            // p[g][f][j][w]; indices wave-uniform -> scalar loads
            const float* pf = p + (((long)(g * FGF + f) * JJ) + j) * WW;
            #pragma unroll
            for (int w = 0; w < WW; ++w) {
                const float pv = pf[w];
                #pragma unroll
                for (int d = 0; d < BK; ++d)
                    acc[f][d] += xw[d + w] * pv;   // y[k0+d] needs x[k0+d-15+w] = xw[d+w]
            }
        }
    }

    // Coalesced float4 stores: k = base + 4t + d
    #pragma unroll
    for (int f = 0; f < FGF; ++f) {
        float4 v = make_float4(acc[f][0], acc[f][1], acc[f][2], acc[f][3]);
        *(float4*)&out[(size_t)(g * FGF + f) * LL + base + 4 * t] = v;
    }
}

// Edge kernel: reference truncates the window against the data edge
// (kernel[0] pinned to x[0] on the left, kernel[W-1] pinned to x[L-1] on the
// right) -- NOT zero padding. 8 blocks (one per group), 256 threads.
__global__ void conv_edges(const float* __restrict__ x, const float* __restrict__ p,
                           const int* __restrict__ rel, float* __restrict__ out)
{
    __shared__ float xl[JJ][WW];   // x[rel[g,j], 0..30]
    __shared__ float xr[JJ][WW];   // x[rel[g,j], L-31..L-1]

    const int g = blockIdx.x;
    const int t = threadIdx.x;

    for (int i = t; i < JJ * WW; i += NTHR) {
        int j = i / WW, w = i % WW;
        int row = rel[g * JJ + j];
        xl[j][w] = x[(long)row * LL + w];
        xr[j][w] = x[(long)row * LL + (LL - WW) + w];
    }
    __syncthreads();

    const int f = t >> 4;      // 0..15
    const int q = t & 15;      // position index
    if (q < PAD1) {
        float a = 0.0f, b = 0.0f;
        for (int j = 0; j < JJ; ++j) {
            const float* pf = p + (((long)(g * FGF + f) * JJ) + j) * WW;
            #pragma unroll
            for (int w = 0; w < WW; ++w) {
                const float pv = pf[w];
                if (w <= q + PAD1) a += xl[j][w] * pv;  // left:  k=q,      w in [0, q+15]
                if (w >= q + 1)    b += xr[j][w] * pv;  // right: k=L-15+q, w in [q+1, 30]
            }
        }
        size_t rowo = (size_t)(g * FGF + f) * LL;
        out[rowo + q] = a;
        out[rowo + (LL - PAD1) + q] = b;
    }
}

extern "C" void kernel_launch(void* const* d_in, const int* in_sizes, int n_in,
                              void* d_out, int out_size, void* d_ws, size_t ws_size,
                              hipStream_t stream)
{
    const float* x   = (const float*)d_in[0];
    const float* p   = (const float*)d_in[1];
    const int*   rel = (const int*)d_in[2];
    float* out = (float*)d_out;

    dim3 grid(LL / TILE, GG);
    conv_main<<<grid, NTHR, 0, stream>>>(x, p, rel, out);
    conv_edges<<<GG, NTHR, 0, stream>>>(x, p, rel, out);
}

// Round 2
// 264.258 us; speedup vs baseline: 2.0461x; 2.0461x over previous
//
#include <hip/hip_runtime.h>

// Problem constants
#define LL    262144
#define GG    8
#define JJ    8
#define FGF   16
#define WW    31
#define PAD1  15
#define NB    512            // k positions per block
#define NTHR  256
#define XTLEN (NB + 32)      // staged positions incl. halo + w=31 pad

typedef __bf16 bf16x8 __attribute__((ext_vector_type(8)));
typedef float  f32x4  __attribute__((ext_vector_type(4)));

__device__ inline unsigned short f2bf(float f) {
    unsigned int u = __float_as_uint(f);
    u = (u + 0x7FFF + ((u >> 16) & 1)) >> 16;   // RNE
    return (unsigned short)u;
}

// MFMA kernel: per group g, Y[16,L] = P[16,256]·XW[256,L]  (K padded 248->256)
// K-block s (K=32) covers w = s*4 + quad (quad=lane>>4), j = 0..7 contiguous.
// B fragment: lane reads xt[pos][0..7] -- one aligned ds_read_b128.
// A fragment: lane reads pw[w][f][0..7] -- loaded once into registers.
// C/D layout (verified m89): col = lane&15, row = quad*4 + reg.
__global__ __launch_bounds__(NTHR, 2)
void conv_mfma(const float* __restrict__ x, const float* __restrict__ p,
               const int* __restrict__ rel, float* __restrict__ out)
{
    __shared__ unsigned short pw[32 * 16 * 8];   // [w][f][j] bf16, w=31 zeroed (8 KB)
    __shared__ unsigned short xt[XTLEN * 8];     // [pos][j]  bf16 (8.5 KB)

    const int t = threadIdx.x;
    const int g = blockIdx.y;
    const long nbase = (long)blockIdx.x * NB;

    // Stage weights transposed: pw[w][f][j] = bf16(p[g][f][j][w]); w=31 -> 0
    for (int i = t; i < 32 * 16 * 8; i += NTHR) {
        int j = i & 7;
        int f = (i >> 3) & 15;
        int w = i >> 7;
        float v = (w < WW) ? p[(((long)(g * FGF + f) * JJ) + j) * WW + w] : 0.0f;
        pw[i] = f2bf(v);
    }

    // Stage x transposed: xt[pos][j] = bf16(x[rel[g,j], nbase + pos - 15])
    {
        const int j  = t >> 5;          // 0..7
        const int p0 = t & 31;
        const float* xr = x + (long)rel[g * JJ + j] * LL;
        #pragma unroll
        for (int c = 0; c < XTLEN / 32; ++c) {   // 17 iters
            int pos = c * 32 + p0;
            long gp = nbase + pos - PAD1;
            float v = (gp >= 0 && gp < LL) ? xr[gp] : 0.0f;
            xt[pos * 8 + j] = f2bf(v);
        }
    }
    __syncthreads();

    const int lane = t & 63;
    const int wid  = t >> 6;      // wave 0..3
    const int col  = lane & 15;
    const int q    = lane >> 4;   // quad

    // A fragments for all 8 K-steps: a[s][i] = P[g, f=col, j=i, w=s*4+q]
    bf16x8 a[8];
    #pragma unroll
    for (int s = 0; s < 8; ++s)
        a[s] = *(const bf16x8*)&pw[((s * 4 + q) * 16 + col) * 8];

    // Wave handles 8 col-tiles (16 cols each), processed in interleaved pairs.
    #pragma unroll
    for (int u = 0; u < 4; ++u) {
        const int t0 = wid * 8 + 2 * u;
        const int t1 = t0 + 1;
        f32x4 acc0 = {0.f, 0.f, 0.f, 0.f};
        f32x4 acc1 = {0.f, 0.f, 0.f, 0.f};
        #pragma unroll
        for (int s = 0; s < 8; ++s) {
            // B fragment: b[i] = xt[tile*16 + col + (s*4+q) ][j=i]  (16B aligned)
            bf16x8 b0 = *(const bf16x8*)&xt[(t0 * 16 + col + s * 4 + q) * 8];
            bf16x8 b1 = *(const bf16x8*)&xt[(t1 * 16 + col + s * 4 + q) * 8];
            acc0 = __builtin_amdgcn_mfma_f32_16x16x32_bf16(a[s], b0, acc0, 0, 0, 0);
            acc1 = __builtin_amdgcn_mfma_f32_16x16x32_bf16(a[s], b1, acc1, 0, 0, 0);
        }
        #pragma unroll
        for (int r = 0; r < 4; ++r) {
            int f = q * 4 + r;
            size_t ro = (size_t)(g * FGF + f) * LL + nbase;
            out[ro + t0 * 16 + col] = acc0[r];
            out[ro + t1 * 16 + col] = acc1[r];
        }
    }
}

// Edge kernel: reference truncates the window at data edges (NOT zero-pad).
// Recomputes first/last 15 columns in exact fp32. 8 blocks, 256 threads.
__global__ void conv_edges(const float* __restrict__ x, const float* __restrict__ p,
                           const int* __restrict__ rel, float* __restrict__ out)
{
    __shared__ float xl[JJ][WW];
    __shared__ float xr[JJ][WW];

    const int g = blockIdx.x;
    const int t = threadIdx.x;

    for (int i = t; i < JJ * WW; i += NTHR) {
        int j = i / WW, w = i % WW;
        int row = rel[g * JJ + j];
        xl[j][w] = x[(long)row * LL + w];
        xr[j][w] = x[(long)row * LL + (LL - WW) + w];
    }
    __syncthreads();

    const int f = t >> 4;
    const int qq = t & 15;
    if (qq < PAD1) {
        float a = 0.0f, b = 0.0f;
        for (int j = 0; j < JJ; ++j) {
            const float* pf = p + (((long)(g * FGF + f) * JJ) + j) * WW;
            #pragma unroll
            for (int w = 0; w < WW; ++w) {
                const float pv = pf[w];
                if (w <= qq + PAD1) a += xl[j][w] * pv;   // left:  k=qq
                if (w >= qq + 1)    b += xr[j][w] * pv;   // right: k=L-15+qq
            }
        }
        size_t rowo = (size_t)(g * FGF + f) * LL;
        out[rowo + qq] = a;
        out[rowo + (LL - PAD1) + qq] = b;
    }
}

extern "C" void kernel_launch(void* const* d_in, const int* in_sizes, int n_in,
                              void* d_out, int out_size, void* d_ws, size_t ws_size,
                              hipStream_t stream)
{
    const float* x   = (const float*)d_in[0];
    const float* p   = (const float*)d_in[1];
    const int*   rel = (const int*)d_in[2];
    float* out = (float*)d_out;

    dim3 grid(LL / NB, GG);
    conv_mfma<<<grid, NTHR, 0, stream>>>(x, p, rel, out);
    conv_edges<<<GG, NTHR, 0, stream>>>(x, p, rel, out);
}

// Round 3
// 249.010 us; speedup vs baseline: 2.1714x; 1.0612x over previous
//
#include <hip/hip_runtime.h>

// Problem constants
#define LL    262144
#define GG    8
#define JJ    8
#define FGF   16
#define WW    31
#define PAD1  15
#define NB    1024           // k positions per block
#define NTHR  256
#define XTLEN (NB + 32)      // staged positions: x[nbase-16 .. nbase+NB+15]

typedef __bf16 bf16x8 __attribute__((ext_vector_type(8)));
typedef float  f32x4  __attribute__((ext_vector_type(4)));

__device__ inline unsigned short f2bf(float f) {
    unsigned int u = __float_as_uint(f);
    u = (u + 0x7FFF + ((u >> 16) & 1)) >> 16;   // RNE
    return (unsigned short)u;
}

// MFMA kernel: per group g, Y[16,L] = P[16,256]·XW[256,L]  (K padded 248->256)
// K-step s covers w = s*4 + quad (quad=lane>>4), j = 0..7 contiguous.
// B fragment: lane reads xt[pos][0..7] -- one aligned ds_read_b128.
// A fragment: lane reads pw[w][f][0..7] -- loaded once into 32 VGPRs.
// C/D layout (m89-verified): col = lane&15, row = quad*4 + reg.
// xt[pos] = x[nbase - 16 + pos]; compute uses xt[k_local + w' + 1].
__global__ __launch_bounds__(NTHR, 4)
void conv_mfma(const float* __restrict__ x, const float* __restrict__ p,
               const int* __restrict__ rel, float* __restrict__ out)
{
    __shared__ unsigned short pw[32 * 16 * 8];   // [w][f][j] bf16, w=31 zeroed (8 KB)
    __shared__ unsigned short xt[XTLEN * 8];     // [pos][j]  bf16 (16.5 KB)

    const int t = threadIdx.x;
    const int g = blockIdx.y;
    const long nbase = (long)blockIdx.x * NB;

    // Stage weights transposed: pw[w][f][j] = bf16(p[g][f][j][w]); w=31 -> 0
    for (int i = t; i < 32 * 16 * 8; i += NTHR) {
        int j = i & 7;
        int f = (i >> 3) & 15;
        int w = i >> 7;
        float v = (w < WW) ? p[(((long)(g * FGF + f) * JJ) + j) * WW + w] : 0.0f;
        pw[i] = f2bf(v);
    }

    // Stage x transposed: xt[pos][j] = bf16(x[rel[g,j], nbase - 16 + pos])
    {
        const int j  = t >> 5;          // 0..7
        const int p0 = t & 31;
        const float* xr = x + (long)rel[g * JJ + j] * LL;
        #pragma unroll
        for (int c = 0; c < XTLEN / 32; ++c) {   // 33 iters
            int pos = c * 32 + p0;
            long gp = nbase - 16 + pos;
            float v = (gp >= 0 && gp < LL) ? xr[gp] : 0.0f;
            xt[pos * 8 + j] = f2bf(v);
        }
    }
    __syncthreads();

    const int lane = t & 63;
    const int wid  = t >> 6;      // wave 0..3
    const int col  = lane & 15;
    const int q    = lane >> 4;   // quad

    // A fragments for all 8 K-steps: a[s][i] = P[g, f=col, j=i, w=s*4+q]
    bf16x8 a[8];
    #pragma unroll
    for (int s = 0; s < 8; ++s)
        a[s] = *(const bf16x8*)&pw[((s * 4 + q) * 16 + col) * 8];

    // Wave handles 16 col-tiles (16 cols each), as 8 interleaved pairs.
    #pragma unroll
    for (int u = 0; u < 8; ++u) {
        const int t0 = wid * 16 + 2 * u;
        const int t1 = t0 + 1;
        f32x4 acc0 = {0.f, 0.f, 0.f, 0.f};
        f32x4 acc1 = {0.f, 0.f, 0.f, 0.f};
        #pragma unroll
        for (int s = 0; s < 8; ++s) {
            // b[i] = xt[t*16 + col + s*4 + q + 1][j=i]  (16B-aligned b128)
            bf16x8 b0 = *(const bf16x8*)&xt[(t0 * 16 + col + s * 4 + q + 1) * 8];
            bf16x8 b1 = *(const bf16x8*)&xt[(t1 * 16 + col + s * 4 + q + 1) * 8];
            acc0 = __builtin_amdgcn_mfma_f32_16x16x32_bf16(a[s], b0, acc0, 0, 0, 0);
            acc1 = __builtin_amdgcn_mfma_f32_16x16x32_bf16(a[s], b1, acc1, 0, 0, 0);
        }
        #pragma unroll
        for (int r = 0; r < 4; ++r) {
            int f = q * 4 + r;
            size_t ro = (size_t)(g * FGF + f) * LL + nbase;
            out[ro + t0 * 16 + col] = acc0[r];
            out[ro + t1 * 16 + col] = acc1[r];
        }
    }
}

// Edge kernel: reference truncates the window at data edges (NOT zero-pad).
// Recomputes first/last 15 columns in exact fp32. All operands staged in LDS
// with coalesced loads (the previous version did 248 per-lane scattered
// global loads per thread with 8 blocks -> ~150us latency-bound).
__global__ void conv_edges(const float* __restrict__ x, const float* __restrict__ p,
                           const int* __restrict__ rel, float* __restrict__ out)
{
    __shared__ float lp[FGF * JJ * WW];   // p[g] : 3968 floats (15.5 KB)
    __shared__ float xl[JJ * WW];         // x[rel[g,j], 0..30]
    __shared__ float xr[JJ * WW];         // x[rel[g,j], L-31..L-1]

    const int g = blockIdx.x;
    const int t = threadIdx.x;

    for (int i = t; i < FGF * JJ * WW; i += NTHR)
        lp[i] = p[(long)g * FGF * JJ * WW + i];

    for (int i = t; i < JJ * WW; i += NTHR) {
        int j = i / WW, w = i % WW;
        long row = rel[g * JJ + j];
        xl[i] = x[row * LL + w];
        xr[i] = x[row * LL + (LL - WW) + w];
    }
    __syncthreads();

    const int f  = t >> 4;
    const int qq = t & 15;
    if (qq < PAD1) {
        float a = 0.0f, b = 0.0f;
        for (int j = 0; j < JJ; ++j) {
            const float* pf = &lp[(f * JJ + j) * WW];
            const float* xlj = &xl[j * WW];
            const float* xrj = &xr[j * WW];
            #pragma unroll
            for (int w = 0; w < WW; ++w) {
                const float pv = pf[w];
                if (w <= qq + PAD1) a += xlj[w] * pv;   // left:  k=qq
                if (w >= qq + 1)    b += xrj[w] * pv;   // right: k=L-15+qq
            }
        }
        size_t rowo = (size_t)(g * FGF + f) * LL;
        out[rowo + qq] = a;
        out[rowo + (LL - PAD1) + qq] = b;
    }
}

extern "C" void kernel_launch(void* const* d_in, const int* in_sizes, int n_in,
                              void* d_out, int out_size, void* d_ws, size_t ws_size,
                              hipStream_t stream)
{
    const float* x   = (const float*)d_in[0];
    const float* p   = (const float*)d_in[1];
    const int*   rel = (const int*)d_in[2];
    float* out = (float*)d_out;

    dim3 grid(LL / NB, GG);
    conv_mfma<<<grid, NTHR, 0, stream>>>(x, p, rel, out);
    conv_edges<<<GG, NTHR, 0, stream>>>(x, p, rel, out);
}

// Round 4
// 242.009 us; speedup vs baseline: 2.2342x; 1.0289x over previous
//
#include <hip/hip_runtime.h>

// Problem constants
#define LL    262144
#define GG    8
#define JJ    8
#define FGF   16
#define WW    31
#define PAD1  15
#define NB    1024           // k positions per block
#define NTHR  256
#define XTLEN (NB + 32)      // staged positions: x[nbase-16 .. nbase+NB+15]

typedef __bf16 bf16x8 __attribute__((ext_vector_type(8)));
typedef float  f32x4  __attribute__((ext_vector_type(4)));

__device__ inline unsigned short f2bf(float f) {
    unsigned int u = __float_as_uint(f);
    u = (u + 0x7FFF + ((u >> 16) & 1)) >> 16;   // RNE
    return (unsigned short)u;
}

// MFMA kernel: per group g, Y[16,L] = P[16,256]·XW[256,L]  (K padded 248->256)
// K-step s covers w = s*4 + quad (quad=lane>>4), j = 0..7 contiguous.
// B fragment for (tile,s): xt[tile*16 + col + s*4 + q + 1][j=0..7] -- one
// aligned ds_read_b128. KEY IDENTITY: frag(tile, s+4) == frag(tile+1, s)
// (positions shift by exactly 16), so a rolling 3-window F0/F1/F2 over tile
// pairs halves B-side LDS reads (68 vs 128 per wave) and keeps 8 ds_reads
// in flight ahead of each 16-MFMA burst. Two acc chains hide MFMA latency.
// C/D layout (m89-verified): col = lane&15, row = quad*4 + reg.
__global__ __launch_bounds__(NTHR, 4)
void conv_mfma(const float* __restrict__ x, const float* __restrict__ p,
               const int* __restrict__ rel, float* __restrict__ out)
{
    __shared__ unsigned short pw[32 * 16 * 8];   // [w][f][j] bf16, w=31 zeroed (8 KB)
    __shared__ unsigned short xt[XTLEN * 8];     // [pos][j]  bf16 (16.5 KB)

    const int t = threadIdx.x;
    const int g = blockIdx.y;
    const long nbase = (long)blockIdx.x * NB;

    // Stage weights transposed, COALESCED global reads (linear over p[g]):
    // i = (f*8 + j)*31 + w  ->  pw[w][f][j]. LDS-write scatter is cheap.
    {
        const float* pg = p + (long)g * FGF * JJ * WW;
        for (int i = t; i < FGF * JJ * WW; i += NTHR) {
            int f = i / (JJ * WW);
            int r = i - f * (JJ * WW);
            int j = r / WW;
            int w = r - j * WW;
            pw[(w * 16 + f) * 8 + j] = f2bf(pg[i]);
        }
        if (t < FGF * JJ) {                    // zero-pad w = 31
            int f = t >> 3, j = t & 7;
            pw[(31 * 16 + f) * 8 + j] = 0;
        }
    }

    // Stage x transposed: xt[pos][j] = bf16(x[rel[g,j], nbase - 16 + pos])
    {
        const int j  = t >> 5;          // 0..7
        const int p0 = t & 31;
        const float* xr = x + (long)rel[g * JJ + j] * LL;
        #pragma unroll
        for (int c = 0; c < XTLEN / 32; ++c) {   // 33 iters
            int pos = c * 32 + p0;
            long gp = nbase - 16 + pos;
            float v = (gp >= 0 && gp < LL) ? xr[gp] : 0.0f;
            xt[pos * 8 + j] = f2bf(v);
        }
    }
    __syncthreads();

    const int lane = t & 63;
    const int wid  = t >> 6;      // wave 0..3, owns cols [wid*256, wid*256+256)
    const int col  = lane & 15;
    const int q    = lane >> 4;   // quad

    // A fragments for all 8 K-steps: a[s][i] = P[g, f=col, j=i, w=s*4+q]
    bf16x8 a[8];
    #pragma unroll
    for (int s = 0; s < 8; ++s)
        a[s] = *(const bf16x8*)&pw[((s * 4 + q) * 16 + col) * 8];

    const int pb = wid * 256 + col + q + 1;   // lane's base xt position

    #define LDX(pos) (*(const bf16x8*)&xt[(pos) * 8])

    // Rolling window: F0 = frags(tile 2u, s=0..3)
    bf16x8 F00 = LDX(pb + 0), F01 = LDX(pb + 4), F02 = LDX(pb + 8), F03 = LDX(pb + 12);

    #pragma unroll
    for (int u = 0; u < 8; ++u) {
        const int o = pb + u * 32;
        // F1 = frags(2u, s=4..7) == frags(2u+1, s=0..3); F2 = frags(2u+1, s=4..7)
        bf16x8 F10 = LDX(o + 16), F11 = LDX(o + 20), F12 = LDX(o + 24), F13 = LDX(o + 28);
        bf16x8 F20 = LDX(o + 32), F21 = LDX(o + 36), F22 = LDX(o + 40), F23 = LDX(o + 44);

        f32x4 acc0 = {0.f, 0.f, 0.f, 0.f};
        f32x4 acc1 = {0.f, 0.f, 0.f, 0.f};
        acc0 = __builtin_amdgcn_mfma_f32_16x16x32_bf16(a[0], F00, acc0, 0, 0, 0);
        acc1 = __builtin_amdgcn_mfma_f32_16x16x32_bf16(a[0], F10, acc1, 0, 0, 0);
        acc0 = __builtin_amdgcn_mfma_f32_16x16x32_bf16(a[1], F01, acc0, 0, 0, 0);
        acc1 = __builtin_amdgcn_mfma_f32_16x16x32_bf16(a[1], F11, acc1, 0, 0, 0);
        acc0 = __builtin_amdgcn_mfma_f32_16x16x32_bf16(a[2], F02, acc0, 0, 0, 0);
        acc1 = __builtin_amdgcn_mfma_f32_16x16x32_bf16(a[2], F12, acc1, 0, 0, 0);
        acc0 = __builtin_amdgcn_mfma_f32_16x16x32_bf16(a[3], F03, acc0, 0, 0, 0);
        acc1 = __builtin_amdgcn_mfma_f32_16x16x32_bf16(a[3], F13, acc1, 0, 0, 0);
        acc0 = __builtin_amdgcn_mfma_f32_16x16x32_bf16(a[4], F10, acc0, 0, 0, 0);
        acc1 = __builtin_amdgcn_mfma_f32_16x16x32_bf16(a[4], F20, acc1, 0, 0, 0);
        acc0 = __builtin_amdgcn_mfma_f32_16x16x32_bf16(a[5], F11, acc0, 0, 0, 0);
        acc1 = __builtin_amdgcn_mfma_f32_16x16x32_bf16(a[5], F21, acc1, 0, 0, 0);
        acc0 = __builtin_amdgcn_mfma_f32_16x16x32_bf16(a[6], F12, acc0, 0, 0, 0);
        acc1 = __builtin_amdgcn_mfma_f32_16x16x32_bf16(a[6], F22, acc1, 0, 0, 0);
        acc0 = __builtin_amdgcn_mfma_f32_16x16x32_bf16(a[7], F13, acc0, 0, 0, 0);
        acc1 = __builtin_amdgcn_mfma_f32_16x16x32_bf16(a[7], F23, acc1, 0, 0, 0);

        // Stores: tile 2u -> acc0, tile 2u+1 -> acc1
        const long kc0 = nbase + (long)(wid * 16 + 2 * u) * 16 + col;
        #pragma unroll
        for (int r = 0; r < 4; ++r) {
            int f = q * 4 + r;
            size_t ro = (size_t)(g * FGF + f) * LL;
            out[ro + kc0]      = acc0[r];
            out[ro + kc0 + 16] = acc1[r];
        }

        F00 = F20; F01 = F21; F02 = F22; F03 = F23;   // roll window
    }
    #undef LDX
}

// Edge kernel: reference truncates the window at data edges (NOT zero-pad).
// Recomputes first/last 15 columns in exact fp32 from LDS-staged operands.
__global__ void conv_edges(const float* __restrict__ x, const float* __restrict__ p,
                           const int* __restrict__ rel, float* __restrict__ out)
{
    __shared__ float lp[FGF * JJ * WW];   // p[g] : 3968 floats (15.5 KB)
    __shared__ float xl[JJ * WW];         // x[rel[g,j], 0..30]
    __shared__ float xr[JJ * WW];         // x[rel[g,j], L-31..L-1]

    const int g = blockIdx.x;
    const int t = threadIdx.x;

    for (int i = t; i < FGF * JJ * WW; i += NTHR)
        lp[i] = p[(long)g * FGF * JJ * WW + i];

    for (int i = t; i < JJ * WW; i += NTHR) {
        int j = i / WW, w = i % WW;
        long row = rel[g * JJ + j];
        xl[i] = x[row * LL + w];
        xr[i] = x[row * LL + (LL - WW) + w];
    }
    __syncthreads();

    const int f  = t >> 4;
    const int qq = t & 15;
    if (qq < PAD1) {
        float a = 0.0f, b = 0.0f;
        for (int j = 0; j < JJ; ++j) {
            const float* pf  = &lp[(f * JJ + j) * WW];
            const float* xlj = &xl[j * WW];
            const float* xrj = &xr[j * WW];
            #pragma unroll
            for (int w = 0; w < WW; ++w) {
                const float pv = pf[w];
                if (w <= qq + PAD1) a += xlj[w] * pv;   // left:  k=qq
                if (w >= qq + 1)    b += xrj[w] * pv;   // right: k=L-15+qq
            }
        }
        size_t rowo = (size_t)(g * FGF + f) * LL;
        out[rowo + qq] = a;
        out[rowo + (LL - PAD1) + qq] = b;
    }
}

extern "C" void kernel_launch(void* const* d_in, const int* in_sizes, int n_in,
                              void* d_out, int out_size, void* d_ws, size_t ws_size,
                              hipStream_t stream)
{
    const float* x   = (const float*)d_in[0];
    const float* p   = (const float*)d_in[1];
    const int*   rel = (const int*)d_in[2];
    float* out = (float*)d_out;

    dim3 grid(LL / NB, GG);
    conv_mfma<<<grid, NTHR, 0, stream>>>(x, p, rel, out);
    conv_edges<<<GG, NTHR, 0, stream>>>(x, p, rel, out);
}